// Round 8
// baseline (30.564 us; speedup 1.0000x reference)
//
#include <hip/hip_runtime.h>
#include <hip/hip_bf16.h>

// x:[8,160,160,64] f32, pos:[8,4096,2] f32, H=W=1280 (device int scalars).
// out:[8,4096,64] f32.
constexpr int B  = 8;
constexpr int Hf = 160;
constexpr int Wf = 160;
constexpr int C  = 64;
constexpr int N  = 4096;
constexpr int NXCD = 8;

// Counting sort by 8x8-pixel tile: 20x20 = 400 bins/batch.
constexpr int TPX  = 8;                // tile pixels
constexpr int TPS  = 20;               // tiles per side
constexpr int BINS = TPS * TPS;        // 400

// ws layout (ints):
//   [cnt B*BINS][cur B*BINS][base B*BINS][idx B*N][pos_sorted 2*B*N floats]
constexpr int WS_CNT  = 0;
constexpr int WS_CUR  = B * BINS;          // 3200
constexpr int WS_BASE = 2 * B * BINS;      // 6400
constexpr int WS_IDX  = 3 * B * BINS;      // 9600
constexpr int WS_POS  = WS_IDX + B * N;    // 42368 (byte off 169472, 8B-aligned)
constexpr size_t WS_NEED = (size_t)(WS_POS + 2 * B * N) * 4;

typedef float f32x4 __attribute__((ext_vector_type(4)));
typedef float f32x2 __attribute__((ext_vector_type(2)));

__device__ __forceinline__ void cubic_weights(float t, float w[4]) {
    const float A = -0.75f;
    float s;
    s = t + 1.0f;
    w[0] = ((A * s - 5.0f * A) * s + 8.0f * A) * s - 4.0f * A;
    s = t;
    w[1] = ((A + 2.0f) * s - (A + 3.0f)) * s * s + 1.0f;
    s = 1.0f - t;
    w[2] = ((A + 2.0f) * s - (A + 3.0f)) * s * s + 1.0f;
    s = 2.0f - t;
    w[3] = ((A * s - 5.0f * A) * s + 8.0f * A) * s - 4.0f * A;
}

// Bin of a point: tile of its clamped base pixel. Must be bit-identical in
// count and scatter passes (it is: same expressions, same inputs).
__device__ __forceinline__ int point_bin(f32x2 p, float Wo, float Ho) {
    float gx = 2.0f * p.x / (Wo - 1.0f) - 1.0f;
    float gy = 2.0f * p.y / (Ho - 1.0f) - 1.0f;
    float ix = ((gx + 1.0f) * (float)Wf - 1.0f) * 0.5f;
    float iy = ((gy + 1.0f) * (float)Hf - 1.0f) * 0.5f;
    int x0 = min(max((int)floorf(ix), 0), Wf - 1);
    int y0 = min(max((int)floorf(iy), 0), Hf - 1);
    return (y0 / TPX) * TPS + (x0 / TPX);
}

// ---- pass 1: count points per (batch, tile) ----
__global__ __launch_bounds__(256)
void count_bins(const float* __restrict__ pos, const int* __restrict__ Hp,
                const int* __restrict__ Wp, int* __restrict__ ws) {
    int pid = blockIdx.x * blockDim.x + threadIdx.x;
    if (pid >= B * N) return;
    int b = pid >> 12;
    f32x2 p = *reinterpret_cast<const f32x2*>(pos + (size_t)pid * 2);
    int bin = point_bin(p, (float)Wp[0], (float)Hp[0]);
    atomicAdd(&ws[WS_CNT + b * BINS + bin], 1);
}

// ---- pass 2: exclusive prefix sum per batch (1 block, wave b = batch b) ----
__global__ __launch_bounds__(512)
void scan_bins(int* __restrict__ ws) {
    int w = threadIdx.x >> 6;      // batch
    int l = threadIdx.x & 63;      // lane
    int carry = 0;
    for (int c = 0; c < (BINS + 63) / 64; ++c) {
        int idx = c * 64 + l;
        int v = (idx < BINS) ? ws[WS_CNT + w * BINS + idx] : 0;
        int incl = v;
        #pragma unroll
        for (int off = 1; off < 64; off <<= 1) {
            int o = __shfl_up(incl, off);
            if (l >= off) incl += o;
        }
        if (idx < BINS) ws[WS_BASE + w * BINS + idx] = carry + incl - v;
        carry += __shfl(incl, 63);
    }
}

// ---- pass 3: scatter points into sorted order (pos pre-gathered) ----
__global__ __launch_bounds__(256)
void scatter_points(const float* __restrict__ pos, const int* __restrict__ Hp,
                    const int* __restrict__ Wp, int* __restrict__ ws) {
    int pid = blockIdx.x * blockDim.x + threadIdx.x;
    if (pid >= B * N) return;
    int b = pid >> 12, n = pid & (N - 1);
    f32x2 p = *reinterpret_cast<const f32x2*>(pos + (size_t)pid * 2);
    int bin = point_bin(p, (float)Wp[0], (float)Hp[0]);
    int slot = ws[WS_BASE + b * BINS + bin]
             + atomicAdd(&ws[WS_CUR + b * BINS + bin], 1);
    int g = b * N + slot;
    ws[WS_IDX + g] = n;
    reinterpret_cast<f32x2*>(ws + WS_POS)[g] = p;
}

// ---- pass 4: gather in tile-sorted order ----
// 16 lanes/point, block = 16 points, batch = blockIdx%8 (XCD-affine).
// Consecutive points share an ~31 KB tile footprint -> L1 reuse instead of
// fresh L2/L3 requests; 4 points/wave share lines within each vmem inst.
__global__ __launch_bounds__(256)
void interp_sorted(const float* __restrict__ x, const int* __restrict__ ws,
                   const int* __restrict__ Hp, const int* __restrict__ Wp,
                   float* __restrict__ out) {
    int g    = blockIdx.x;
    int b    = g & (NXCD - 1);
    int slot = g >> 3;
    int q    = threadIdx.x & 15;
    int pib  = threadIdx.x >> 4;
    int i    = slot * 16 + pib;          // sorted position within batch

    f32x2 p = reinterpret_cast<const f32x2*>(ws + WS_POS)[b * N + i];
    int   n = ws[WS_IDX + b * N + i];
    float Wo = (float)Wp[0], Ho = (float)Hp[0];

    float gx = 2.0f * p.x / (Wo - 1.0f) - 1.0f;
    float gy = 2.0f * p.y / (Ho - 1.0f) - 1.0f;
    float ix = ((gx + 1.0f) * (float)Wf - 1.0f) * 0.5f;
    float iy = ((gy + 1.0f) * (float)Hf - 1.0f) * 0.5f;

    float fx = floorf(ix), fy = floorf(iy);
    float tx = ix - fx,    ty = iy - fy;
    int x0 = (int)fx, y0 = (int)fy;

    float wx[4], wy[4];
    cubic_weights(tx, wx);
    cubic_weights(ty, wy);

    int yc[4], xc[4];
    #pragma unroll
    for (int k = 0; k < 4; ++k) {
        int yi = y0 - 1 + k;
        wy[k] = (yi >= 0 && yi < Hf) ? wy[k] : 0.0f;
        yc[k] = min(max(yi, 0), Hf - 1);
        int xj = x0 - 1 + k;
        wx[k] = (xj >= 0 && xj < Wf) ? wx[k] : 0.0f;
        xc[k] = min(max(xj, 0), Wf - 1);
    }

    const float* xb = x + (size_t)b * (Hf * Wf * C) + q * 4;

    f32x4 v[4][4];
    #pragma unroll
    for (int k = 0; k < 4; ++k) {
        const float* row = xb + (size_t)yc[k] * (Wf * C);
        #pragma unroll
        for (int j = 0; j < 4; ++j)
            v[k][j] = *reinterpret_cast<const f32x4*>(row + (size_t)xc[j] * C);
    }

    f32x4 acc = {0.f, 0.f, 0.f, 0.f};
    #pragma unroll
    for (int k = 0; k < 4; ++k) {
        #pragma unroll
        for (int j = 0; j < 4; ++j) {
            float w = wy[k] * wx[j];
            acc.x = fmaf(w, v[k][j].x, acc.x);
            acc.y = fmaf(w, v[k][j].y, acc.y);
            acc.z = fmaf(w, v[k][j].z, acc.z);
            acc.w = fmaf(w, v[k][j].w, acc.w);
        }
    }

    f32x4* op = reinterpret_cast<f32x4*>(out + ((size_t)b * N + n) * C + q * 4);
    __builtin_nontemporal_store(acc, op);
}

// ---- fallback: direct (R4) kernel if ws too small ----
__global__ __launch_bounds__(256)
void interp_direct(const float* __restrict__ x, const float* __restrict__ pos,
                   const int* __restrict__ Hp, const int* __restrict__ Wp,
                   float* __restrict__ out) {
    int blk  = blockIdx.x;
    int b    = blk & (NXCD - 1);
    int slot = blk >> 3;
    int q    = threadIdx.x & 15;
    int pib  = threadIdx.x >> 4;
    int pnt  = b * N + slot * 16 + pib;

    f32x2 p = *reinterpret_cast<const f32x2*>(pos + (size_t)pnt * 2);
    float Wo = (float)Wp[0], Ho = (float)Hp[0];
    float gx = 2.0f * p.x / (Wo - 1.0f) - 1.0f;
    float gy = 2.0f * p.y / (Ho - 1.0f) - 1.0f;
    float ix = ((gx + 1.0f) * (float)Wf - 1.0f) * 0.5f;
    float iy = ((gy + 1.0f) * (float)Hf - 1.0f) * 0.5f;
    float fx = floorf(ix), fy = floorf(iy);
    float tx = ix - fx,    ty = iy - fy;
    int x0 = (int)fx, y0 = (int)fy;

    float wx[4], wy[4];
    cubic_weights(tx, wx);
    cubic_weights(ty, wy);

    int yc[4], xc[4];
    #pragma unroll
    for (int k = 0; k < 4; ++k) {
        int yi = y0 - 1 + k;
        wy[k] = (yi >= 0 && yi < Hf) ? wy[k] : 0.0f;
        yc[k] = min(max(yi, 0), Hf - 1);
        int xj = x0 - 1 + k;
        wx[k] = (xj >= 0 && xj < Wf) ? wx[k] : 0.0f;
        xc[k] = min(max(xj, 0), Wf - 1);
    }

    const float* xb = x + (size_t)b * (Hf * Wf * C) + q * 4;
    f32x4 v[4][4];
    #pragma unroll
    for (int k = 0; k < 4; ++k) {
        const float* row = xb + (size_t)yc[k] * (Wf * C);
        #pragma unroll
        for (int j = 0; j < 4; ++j)
            v[k][j] = *reinterpret_cast<const f32x4*>(row + (size_t)xc[j] * C);
    }
    f32x4 acc = {0.f, 0.f, 0.f, 0.f};
    #pragma unroll
    for (int k = 0; k < 4; ++k) {
        #pragma unroll
        for (int j = 0; j < 4; ++j) {
            float w = wy[k] * wx[j];
            acc.x = fmaf(w, v[k][j].x, acc.x);
            acc.y = fmaf(w, v[k][j].y, acc.y);
            acc.z = fmaf(w, v[k][j].z, acc.z);
            acc.w = fmaf(w, v[k][j].w, acc.w);
        }
    }
    f32x4* op = reinterpret_cast<f32x4*>(out + (size_t)pnt * C + q * 4);
    __builtin_nontemporal_store(acc, op);
}

extern "C" void kernel_launch(void* const* d_in, const int* in_sizes, int n_in,
                              void* d_out, int out_size, void* d_ws, size_t ws_size,
                              hipStream_t stream) {
    const float* x   = (const float*)d_in[0];
    const float* pos = (const float*)d_in[1];
    const int*   Hp  = (const int*)d_in[2];
    const int*   Wp  = (const int*)d_in[3];
    float* out = (float*)d_out;

    if (ws_size < WS_NEED) {
        interp_direct<<<B * (N / 16), 256, 0, stream>>>(x, pos, Hp, Wp, out);
        return;
    }

    int* ws = (int*)d_ws;
    // zero cnt + cur (adjacent, 2*B*BINS ints = 25.6 KB)
    hipMemsetAsync(ws, 0, (size_t)2 * B * BINS * sizeof(int), stream);

    count_bins<<<(B * N) / 256, 256, 0, stream>>>(pos, Hp, Wp, ws);
    scan_bins<<<1, 512, 0, stream>>>(ws);
    scatter_points<<<(B * N) / 256, 256, 0, stream>>>(pos, Hp, Wp, ws);
    interp_sorted<<<B * (N / 16), 256, 0, stream>>>(x, ws, Hp, Wp, out);
}